// Round 3
// baseline (138.731 us; speedup 1.0000x reference)
//
#include <hip/hip_runtime.h>

#define PP 96
#define NB (PP*PP)            // 9216
#define NCH (NB/64)           // 144 64-chunks
#define PROB_THR 0.9f
#define FAST_CAP 1024         // fast path: M <= 1024, W <= 16
#define LSTRIDE 1034          // padded LDS row stride (u64): even (16B), 2-way max aliasing

typedef unsigned long long u64;
typedef unsigned int u32;

// Bit-identical decode core (no FMA contraction; rintf == round-half-even).
__device__ __forceinline__ void decode_core(int n, float xv, float yv, float wv, float hv,
                                            float& X1, float& Y1, float& X2, float& Y2)
{
    int i = n / PP;
    int j = n - i * PP;
    float bx = __fadd_rn(__fmul_rn(xv, 16.0f), (float)i * 16.0f);
    float by = __fadd_rn(__fmul_rn(yv, 16.0f), (float)j * 16.0f);
    float bw = __fmul_rn(wv, 1536.0f);
    float bh = __fmul_rn(hv, 1536.0f);
    X1 = rintf(bx);
    Y1 = rintf(by);
    X2 = rintf(__fadd_rn(bw, bx));
    Y2 = rintf(__fadd_rn(bh, by));
}

__device__ __forceinline__ void decode_box(const float* __restrict__ x, int n,
                                           float& X1, float& Y1, float& X2, float& Y2)
{
    decode_core(n, x[NB + n], x[2 * NB + n], x[3 * NB + n], x[4 * NB + n], X1, Y1, X2, Y2);
}

// Exact-equivalent IoU>0.5 without division (R5-R10 validated on HW).
__device__ __forceinline__ int iou_hit_nodiv(float ix1, float iy1, float ix2, float iy2, float iar,
                                             float jx1, float jy1, float jx2, float jy2, float jar)
{
    float xx1 = fmaxf(ix1, jx1), yy1 = fmaxf(iy1, jy1);
    float xx2 = fminf(ix2, jx2), yy2 = fminf(iy2, jy2);
    float iw = fmaxf(__fsub_rn(xx2, xx1), 0.0f);
    float ih = fmaxf(__fsub_rn(yy2, yy1), 0.0f);
    float inter = __fmul_rn(iw, ih);
    float uni = __fsub_rn(__fadd_rn(iar, jar), inter);
    return (uni > 0.0f && __fadd_rn(inter, inter) > uni) ? 1 : 0;
}

__device__ __forceinline__ int iou_hit_div(float ix1, float iy1, float ix2, float iy2, float iar,
                                           float jx1, float jy1, float jx2, float jy2, float jar)
{
    float xx1 = fmaxf(ix1, jx1), yy1 = fmaxf(iy1, jy1);
    float xx2 = fminf(ix2, jx2), yy2 = fminf(iy2, jy2);
    float iw = fmaxf(__fsub_rn(xx2, xx1), 0.0f);
    float ih = fmaxf(__fsub_rn(yy2, yy1), 0.0f);
    float inter = __fmul_rn(iw, ih);
    float uni = __fsub_rn(__fadd_rn(iar, jar), inter);
    return (uni > 0.0f && __fdiv_rn(inter, uni) > 0.5f) ? 1 : 0;
}

// ---------------------------------------------------------------------------
// Dispatch 1: k_front, 32 blocks x 256 — fused sort + adjacency, R3 version.
// Each block: masks+prefix+compact (validated), then DESCENDING BITONIC SORT
// of the 1024 padded u64 keys in LDS (unique keys -> identical placement to
// the validated rank scheme, ~55 short passes instead of ~3840 serial u64
// compares/thread), decode sorted boxes into LDS, then the validated k_adj
// ballot loop for this block's 32 rows. Block 0 also writes gbox/gss.
// ---------------------------------------------------------------------------
__global__ void __launch_bounds__(256) k_front(
    const float* __restrict__ x,
    float* __restrict__ gss, float4* __restrict__ gbox,
    u64* __restrict__ skeys, int* __restrict__ counter,
    u64* __restrict__ adjT, int ws_ok)
{
    __shared__ u64 lmask[NCH];
    __shared__ int pc[NCH], loff[NCH];
    __shared__ int sM;
    __shared__ u64 kdb[FAST_CAP];
    __shared__ float4 lb[FAST_CAP];
    __shared__ float la[FAST_CAP];

    const int tid = threadIdx.x;
    const int lane = tid & 63;
    const int wv = tid >> 6;                  // 4 waves; 36 chunks each
    const int b = blockIdx.x;

    #pragma unroll
    for (int g = 0; g < 36; g += 6) {
        float sv[6];
        #pragma unroll
        for (int u = 0; u < 6; ++u)
            sv[u] = x[((wv * 36 + g + u) << 6) + lane];
        #pragma unroll
        for (int u = 0; u < 6; ++u) {
            u64 m = __ballot(sv[u] > PROB_THR);
            if (lane == 0) lmask[wv * 36 + g + u] = m;
        }
    }
    __syncthreads();
    if (tid < NCH) pc[tid] = __popcll(lmask[tid]);
    __syncthreads();
    if (tid < 64) {                           // wave-parallel prefix (validated)
        int acc = 0;
        for (int seg = 0; seg < 3; ++seg) {
            int c = (seg << 6) + lane;
            int pv = (c < NCH) ? pc[c] : 0;
            int v = pv;
            #pragma unroll
            for (int off = 1; off < 64; off <<= 1) {
                int u = __shfl_up(v, off);
                if (lane >= off) v += u;
            }
            if (c < NCH) loff[c] = acc + v - pv;
            acc += __shfl(v, 63);
        }
        if (lane == 0) sM = acc;
    }
    __syncthreads();
    const int M = sM;
    const bool fast = (M <= FAST_CAP) && ws_ok;
    if (b == 0 && tid == 0) counter[0] = M;

    if (!fast) {
        if (b == 0) {
            for (int c = wv; c < NCH; c += 4) {
                float s = x[(c << 6) + lane];
                u64 m = lmask[c];
                if ((m >> lane) & 1ull) {
                    int pos = loff[c] + __popcll(m & ((1ull << lane) - 1ull));
                    int n = (c << 6) + lane;
                    skeys[pos] = ((u64)__float_as_uint(s) << 32) | (u64)(NB - 1 - n);
                }
            }
        }
        return;
    }
    // blocks with an empty adjacency slice (and no side outputs) exit early
    if (b != 0 && (b << 5) >= M) return;

    for (int c = wv; c < NCH; c += 4) {
        float s = x[(c << 6) + lane];          // L1-warm
        u64 m = lmask[c];
        if ((m >> lane) & 1ull) {
            int pos = loff[c] + __popcll(m & ((1ull << lane) - 1ull));
            int n = (c << 6) + lane;
            kdb[pos] = ((u64)__float_as_uint(s) << 32) | (u64)(NB - 1 - n);
        }
    }
    for (int q = M + tid; q < FAST_CAP; q += 256) kdb[q] = 0ull;  // pad (sorts last)
    __syncthreads();

    // ---- descending bitonic sort of kdb[1024] (unique keys, exact order) ----
    #pragma unroll 1
    for (int k = 2; k <= FAST_CAP; k <<= 1) {
        #pragma unroll 1
        for (int j = k >> 1; j > 0; j >>= 1) {
            #pragma unroll
            for (int e0 = 0; e0 < FAST_CAP; e0 += 256) {
                int e = e0 + tid;
                int p = e ^ j;
                if (p > e) {
                    u64 a = kdb[e], c2 = kdb[p];
                    bool desc = ((e & k) == 0);
                    if (desc ? (a < c2) : (a > c2)) { kdb[e] = c2; kdb[p] = a; }
                }
            }
            __syncthreads();
        }
    }

    // ---- decode sorted slots + scatter boxes/areas into LDS (global, b==0) ----
    #pragma unroll
    for (int g = 0; g < 4; ++g) {
        int slot = (g << 8) + tid;
        u64 key = kdb[slot];
        int n0 = NB - 1 - (int)(key & 0xFFFFFFFFull);   // pad key -> n0 = NB-1 (safe)
        float xv = x[NB + n0];
        float yv = x[2 * NB + n0];
        float wvv = x[3 * NB + n0];
        float hvv = x[4 * NB + n0];
        if (slot < M) {
            float X1, Y1, X2, Y2;
            decode_core(n0, xv, yv, wvv, hvv, X1, Y1, X2, Y2);
            float4 bb = make_float4(X1, Y1, X2, Y2);
            lb[slot] = bb;
            la[slot] = __fmul_rn(__fsub_rn(X2, X1), __fsub_rn(Y2, Y1));
            if (b == 0) {
                gbox[slot] = bb;
                gss[slot] = __uint_as_float((u32)(key >> 32));
            }
        }
    }
    __syncthreads();

    // ---- adjacency slice: 32 rows per block (validated k_adj body) ----
    const int W = (M + 63) >> 6;
    #pragma unroll
    for (int r = 0; r < 8; ++r) {
        int i = (b << 5) + (r << 2) + wv;
        if (i >= M) break;
        float4 bi = lb[i];
        float iar = la[i];
        for (int kk = 0; kk < W; ++kk) {
            int j = (kk << 6) + lane;
            float4 bj = lb[j & (FAST_CAP - 1)];
            float jar = la[j & (FAST_CAP - 1)];
            int hit = (j < M) && iou_hit_nodiv(bi.x, bi.y, bi.z, bi.w, iar,
                                               bj.x, bj.y, bj.z, bj.w, jar);
            u64 mm = __ballot(hit);
            if (lane == 0) adjT[((size_t)kk << 10) + i] = mm;
        }
    }
}

// ---------------------------------------------------------------------------
// Dispatch 2: k_sweep, 1 block x 256 — byte-identical to R2 (validated).
// ---------------------------------------------------------------------------
__global__ void __launch_bounds__(256) k_sweep(
    const float* __restrict__ x, float* __restrict__ out,
    float* __restrict__ gss, float4* __restrict__ gbox,
    const u64* __restrict__ skeys, const int* __restrict__ counter,
    const u64* __restrict__ adjT, int ws_ok)
{
    __shared__ __align__(16) u64 Lds[16 * LSTRIDE];   // 132,352 B
    __shared__ u64 keepw[NCH];

    const int tid = threadIdx.x, lane = tid & 63;

    // zero the whole out buffer (6*NB floats = 13824 float4); fire-and-forget
    {
        float4 z4 = make_float4(0.f, 0.f, 0.f, 0.f);
        for (int q = tid; q < 13824; q += 256)
            ((float4*)out)[q] = z4;
    }

    int M = counter[0]; if (M > NB) M = NB;
    const int W = (M + 63) >> 6;
    const bool fast = (M <= FAST_CAP) && ws_ok;

    if (fast) {
        // ---- stage adjT -> LDS: 4 rounds x 8-deep batched 16B (R9-validated) ----
        const int npair = W << 9;                     // <= 8192 ulonglong2
        const ulonglong2* gp = (const ulonglong2*)adjT;
        for (int r = 0; r < 4; ++r) {
            int fb = (r << 11) + tid;
            ulonglong2 v[8];
            #pragma unroll
            for (int u = 0; u < 8; ++u) {
                int f = fb + (u << 8);
                v[u] = (f < npair) ? gp[f] : make_ulonglong2(0ull, 0ull);
            }
            #pragma unroll
            for (int u = 0; u < 8; ++u) {
                int f = fb + (u << 8);
                if (f < npair) {
                    int w = f >> 9, r2 = f & 511;
                    ((ulonglong2*)Lds)[w * (LSTRIDE >> 1) + r2] = v[u];
                }
            }
        }
        __syncthreads();

        if (tid < 64) {
            const int wl = (lane < W) ? lane : 0;
            u32 supl = 0u, suph = 0u, dl = 0u, dh = 0u;
            u64 mykw = 0ull;
            const int nrb = (M + 31) >> 5;
            for (int rb = 0; rb < nrb; ++rb) {
                const int c = rb >> 1;
                const int base = rb << 5;
                const ulonglong2* crow = (const ulonglong2*)(Lds + (size_t)c * LSTRIDE + base);
                const ulonglong2* rrow = (const ulonglong2*)(Lds + (size_t)wl * LSTRIDE + base);
                // batch-issue BOTH columns as 32 independent b128 reads -> regs
                u64 colb[32], rowb[32];
                #pragma unroll
                for (int q = 0; q < 16; ++q) {
                    ulonglong2 t2 = crow[q];
                    colb[2 * q] = t2.x; colb[2 * q + 1] = t2.y;
                }
                #pragma unroll
                for (int q = 0; q < 16; ++q) {
                    ulonglong2 t2 = rrow[q];
                    rowb[2 * q] = t2.x; rowb[2 * q + 1] = t2.y;
                }
                if (!(rb & 1)) {
                    if (rb == 0) { dl = 0u; dh = 0u; }
                    else { dl = (u32)__shfl((int)supl, c); dh = (u32)__shfl((int)suph, c); }
                    int rem = M - (c << 6);           // tail: rows >= M suppressed
                    if (rem < 64) {
                        if (rem >= 32) dh |= 0xFFFFFFFFu << (rem - 32);
                        else { dh = 0xFFFFFFFFu; dl |= 0xFFFFFFFFu << rem; }
                    }
                }
                u32 kw = 0u;
                if (!(rb & 1)) {
                    #pragma unroll
                    for (int t = 0; t < 32; ++t) {
                        u32 bbit = (dl >> t) & 1u;
                        u32 m = bbit - 1u;            // ~0 kept, 0 suppressed
                        dl |= (u32)colb[t] & m;
                        dh |= (u32)(colb[t] >> 32) & m;
                        kw |= m & (1u << t);
                    }
                } else {
                    #pragma unroll
                    for (int t = 0; t < 32; ++t) {
                        u32 bbit = (dh >> t) & 1u;
                        u32 m = bbit - 1u;
                        dl |= (u32)colb[t] & m;
                        dh |= (u32)(colb[t] >> 32) & m;
                        kw |= m & (1u << t);
                    }
                }
                // constant-trip masked suppression-OR (values already in regs)
                #pragma unroll
                for (int t = 0; t < 32; ++t) {
                    u32 m = 0u - ((kw >> t) & 1u);    // ~0 if kept
                    supl |= (u32)rowb[t] & m;
                    suph |= (u32)(rowb[t] >> 32) & m;
                }
                mykw |= (lane == c) ? ((u64)kw << ((rb & 1) << 5)) : 0ull;
            }
            keepw[lane] = mykw;
        }
    } else {
        // slow path (M > 1024): counting rank + decode + single-wave sweep.
        for (int t = tid; t < M; t += 256) {
            u64 key = skeys[t];
            int r = 0;
            for (int q = 0; q < M; ++q) r += (skeys[q] > key) ? 1 : 0;
            int n = NB - 1 - (int)(key & 0xFFFFFFFFull);
            float X1, Y1, X2, Y2;
            decode_box(x, n, X1, Y1, X2, Y2);
            gbox[r] = make_float4(X1, Y1, X2, Y2);
            gss[r] = __uint_as_float((u32)(key >> 32));
        }
        __threadfence();
        __syncthreads();
        if (tid < 64) {
            u64 kbs[3] = {0ull, 0ull, 0ull};
            for (int i = 0; i < M; ++i) {
                float4 bi = gbox[i];
                float iar = __fmul_rn(__fsub_rn(bi.z, bi.x), __fsub_rn(bi.w, bi.y));
                int hit = 0;
                int nk = (i > lane) ? ((i - lane + 63) >> 6) : 0;
                for (int w = 0; w < 3 && !hit; ++w) {
                    int klim = nk - (w << 6);
                    if (klim <= 0) break;
                    u64 bits = kbs[w];
                    if (klim < 64) bits &= ((1ull << klim) - 1ull);
                    while (bits) {
                        int kk2 = __builtin_ctzll(bits);
                        bits &= bits - 1ull;
                        int jj = lane + (((w << 6) + kk2) << 6);
                        float4 bj = gbox[jj];
                        float jar = __fmul_rn(__fsub_rn(bj.z, bj.x), __fsub_rn(bj.w, bj.y));
                        if (iou_hit_div(bi.x, bi.y, bi.z, bi.w, iar,
                                        bj.x, bj.y, bj.z, bj.w, jar)) { hit = 1; break; }
                    }
                }
                int suppressed = __any(hit);
                if (!suppressed && lane == (i & 63)) kbs[(i >> 6) >> 6] |= 1ull << ((i >> 6) & 63);
            }
            int NWrd = (M + 63) >> 6;
            for (int wd = 0; wd < NWrd; ++wd) {
                u64 bit = (kbs[wd >> 6] >> (wd & 63)) & 1ull;
                u64 word = __ballot(bit != 0);
                if (lane == 0 && wd < NCH) keepw[wd] = word;
            }
        }
    }
    __syncthreads();

    // emit kept rows only (rest zeroed by the pass at the top; those stores
    // are drained by the barriers above)
    for (int i = tid; i < M; i += 256) {
        if ((keepw[i >> 6] >> (i & 63)) & 1ull) {
            float4 bb = gbox[i];
            out[i * 5 + 0] = gss[i];
            out[i * 5 + 1] = bb.x;
            out[i * 5 + 2] = bb.y;
            out[i * 5 + 3] = __fsub_rn(bb.z, bb.x);
            out[i * 5 + 4] = __fsub_rn(bb.w, bb.y);
            out[5 * NB + i] = 1.0f;
        }
    }
}

extern "C" void kernel_launch(void* const* d_in, const int* in_sizes, int n_in,
                              void* d_out, int out_size, void* d_ws, size_t ws_size,
                              hipStream_t stream) {
    const float* x = (const float*)d_in[0];
    float* out = (float*)d_out;

    char* ws = (char*)d_ws;
    int* counter = (int*)ws;
    float*  gss  = (float*)(ws + 16);
    float4* gbox = (float4*)(ws + 16 + (size_t)4 * NB);
    u64*    adjT = (u64*)(ws + 16 + (size_t)4 * NB + (size_t)16 * NB);
    u64*    skeys = (u64*)((char*)adjT + (size_t)16384 * 8);
    const size_t NEEDED = 16 + (size_t)4 * NB + (size_t)16 * NB
                        + (size_t)16384 * 8 + (size_t)8 * NB;      // 389,136
    int ws_ok = (ws_size >= NEEDED) ? 1 : 0;

    k_front<<<32, 256, 0, stream>>>(x, gss, gbox, skeys, counter, adjT, ws_ok);
    k_sweep<<<1, 256, 0, stream>>>(x, out, gss, gbox, skeys, counter, adjT, ws_ok);
}

// Round 4
// 113.324 us; speedup vs baseline: 1.2242x; 1.2242x over previous
//
#include <hip/hip_runtime.h>

#define PP 96
#define NB (PP*PP)            // 9216
#define NCH (NB/64)           // 144 64-chunks
#define PROB_THR 0.9f
#define FAST_CAP 1024         // fast path: M <= 1024, W <= 16

typedef unsigned long long u64;
typedef unsigned int u32;

// Bit-identical decode core (no FMA contraction; rintf == round-half-even).
__device__ __forceinline__ void decode_core(int n, float xv, float yv, float wv, float hv,
                                            float& X1, float& Y1, float& X2, float& Y2)
{
    int i = n / PP;
    int j = n - i * PP;
    float bx = __fadd_rn(__fmul_rn(xv, 16.0f), (float)i * 16.0f);
    float by = __fadd_rn(__fmul_rn(yv, 16.0f), (float)j * 16.0f);
    float bw = __fmul_rn(wv, 1536.0f);
    float bh = __fmul_rn(hv, 1536.0f);
    X1 = rintf(bx);
    Y1 = rintf(by);
    X2 = rintf(__fadd_rn(bw, bx));
    Y2 = rintf(__fadd_rn(bh, by));
}

__device__ __forceinline__ void decode_box(const float* __restrict__ x, int n,
                                           float& X1, float& Y1, float& X2, float& Y2)
{
    decode_core(n, x[NB + n], x[2 * NB + n], x[3 * NB + n], x[4 * NB + n], X1, Y1, X2, Y2);
}

// Exact-equivalent IoU>0.5 without division (validated on HW).
__device__ __forceinline__ int iou_hit_nodiv(float ix1, float iy1, float ix2, float iy2, float iar,
                                             float jx1, float jy1, float jx2, float jy2, float jar)
{
    float xx1 = fmaxf(ix1, jx1), yy1 = fmaxf(iy1, jy1);
    float xx2 = fminf(ix2, jx2), yy2 = fminf(iy2, jy2);
    float iw = fmaxf(__fsub_rn(xx2, xx1), 0.0f);
    float ih = fmaxf(__fsub_rn(yy2, yy1), 0.0f);
    float inter = __fmul_rn(iw, ih);
    float uni = __fsub_rn(__fadd_rn(iar, jar), inter);
    return (uni > 0.0f && __fadd_rn(inter, inter) > uni) ? 1 : 0;
}

__device__ __forceinline__ int iou_hit_div(float ix1, float iy1, float ix2, float iy2, float iar,
                                           float jx1, float jy1, float jx2, float jy2, float jar)
{
    float xx1 = fmaxf(ix1, jx1), yy1 = fmaxf(iy1, jy1);
    float xx2 = fminf(ix2, jx2), yy2 = fminf(iy2, jy2);
    float iw = fmaxf(__fsub_rn(xx2, xx1), 0.0f);
    float ih = fmaxf(__fsub_rn(yy2, yy1), 0.0f);
    float inter = __fmul_rn(iw, ih);
    float uni = __fsub_rn(__fadd_rn(iar, jar), inter);
    return (uni > 0.0f && __fdiv_rn(inter, uni) > 0.5f) ? 1 : 0;
}

// ---------------------------------------------------------------------------
// Dispatch 1: k_sort, 16 blocks x 256 — EXACT R0 structure (rank-own-64,
// fast ~5us), plus fire-and-forget out-zeroing (16-way split) and flags
// zeroing (ordered before dispatch 2 by the dispatch boundary).
// ---------------------------------------------------------------------------
__global__ void __launch_bounds__(256) k_sort(
    const float* __restrict__ x, float* __restrict__ out,
    float* __restrict__ gss, float4* __restrict__ gbox,
    u64* __restrict__ skeys, int* __restrict__ counter,
    u32* __restrict__ flags, int ws_ok)
{
    __shared__ u64 lmask[NCH];
    __shared__ int pc[NCH], loff[NCH];
    __shared__ int sM;
    __shared__ u64 kdb[FAST_CAP];
    __shared__ int prank[256];

    const int tid = threadIdx.x;
    const int lane = tid & 63;
    const int wv = tid >> 6;                  // 4 waves; 36 chunks each
    const int b = blockIdx.x;

    // fire-and-forget: zero out (6*NB floats = 13824 float4 over 16 blocks)
    {
        float4 z4 = make_float4(0.f, 0.f, 0.f, 0.f);
        for (int q = tid; q < 864; q += 256)
            ((float4*)out)[b * 864 + q] = z4;
        if (b == 0 && tid < 64) flags[tid] = 0u;
    }

    #pragma unroll
    for (int g = 0; g < 36; g += 6) {
        float sv[6];
        #pragma unroll
        for (int u = 0; u < 6; ++u)
            sv[u] = x[((wv * 36 + g + u) << 6) + lane];
        #pragma unroll
        for (int u = 0; u < 6; ++u) {
            u64 m = __ballot(sv[u] > PROB_THR);
            if (lane == 0) lmask[wv * 36 + g + u] = m;
        }
    }
    __syncthreads();
    if (tid < NCH) pc[tid] = __popcll(lmask[tid]);
    __syncthreads();
    if (tid < 64) {                           // wave-parallel prefix (validated)
        int acc = 0;
        for (int seg = 0; seg < 3; ++seg) {
            int c = (seg << 6) + lane;
            int pv = (c < NCH) ? pc[c] : 0;
            int v = pv;
            #pragma unroll
            for (int off = 1; off < 64; off <<= 1) {
                int u = __shfl_up(v, off);
                if (lane >= off) v += u;
            }
            if (c < NCH) loff[c] = acc + v - pv;
            acc += __shfl(v, 63);
        }
        if (lane == 0) sM = acc;
    }
    __syncthreads();
    const int M = sM;
    const bool fast = (M <= FAST_CAP) && ws_ok;
    if (b == 0 && tid == 0) counter[0] = M;

    if (!fast) {
        if (b == 0) {
            for (int c = wv; c < NCH; c += 4) {
                float s = x[(c << 6) + lane];
                u64 m = lmask[c];
                if ((m >> lane) & 1ull) {
                    int pos = loff[c] + __popcll(m & ((1ull << lane) - 1ull));
                    int n = (c << 6) + lane;
                    skeys[pos] = ((u64)__float_as_uint(s) << 32) | (u64)(NB - 1 - n);
                }
            }
        }
        return;
    }

    for (int c = wv; c < NCH; c += 4) {
        float s = x[(c << 6) + lane];          // L1-warm
        u64 m = lmask[c];
        if ((m >> lane) & 1ull) {
            int pos = loff[c] + __popcll(m & ((1ull << lane) - 1ull));
            int n = (c << 6) + lane;
            kdb[pos] = ((u64)__float_as_uint(s) << 32) | (u64)(NB - 1 - n);
        }
    }
    for (int q = M + tid; q < FAST_CAP; q += 256) kdb[q] = 0ull;  // pad
    __syncthreads();

    const int cand = (b << 6) + lane;          // < 1024 always
    const u64 k0 = kdb[cand];
    const int n0 = NB - 1 - (int)(k0 & 0xFFFFFFFFull);
    float xv0 = x[NB + n0], yv0 = x[2 * NB + n0];
    float wv0 = x[3 * NB + n0], hv0 = x[4 * NB + n0];
    int r = 0;
    const int nck = (M + 63) >> 6;
    for (int ch = wv; ch < nck; ch += 4) {     // wave-uniform chunk slice
        u64 kq = kdb[(ch << 6) + lane];
        u32 qlo = (u32)kq, qhi = (u32)(kq >> 32);
        #pragma unroll
        for (int i = 0; i < 64; ++i) {
            u32 blo = (u32)__builtin_amdgcn_readlane((int)qlo, i);
            u32 bhi = (u32)__builtin_amdgcn_readlane((int)qhi, i);
            u64 kb = ((u64)bhi << 32) | (u64)blo;
            r += (kb > k0) ? 1 : 0;
        }
    }
    prank[tid] = r;
    __syncthreads();
    if (tid < 64 && cand < M) {
        int rk = prank[tid] + prank[64 + tid] + prank[128 + tid] + prank[192 + tid];
        float X1, Y1, X2, Y2;
        decode_core(n0, xv0, yv0, wv0, hv0, X1, Y1, X2, Y2);
        gbox[rk] = make_float4(X1, Y1, X2, Y2);
        gss[rk] = __uint_as_float((u32)(k0 >> 32));
    }
}

// ---------------------------------------------------------------------------
// Dispatch 2: k_adjsweep, 65 blocks x 256 — producer-consumer fusion.
// Blocks 1..64: old k_adj body for 16 rows each; publish flags[g] with a
//   device-scope release store after a full-block store drain.
// Block 0: the validated sweep, but streaming — double-buffered 4KB
//   row-blocks (2 x 16 chunks x 32 rows) staged JIT by waves 1-3 while
//   wave 0 runs the (byte-identical) decision/OR chain on the other buffer.
// Deadlock-free: producers wait on nothing; 65 blocks are all co-resident.
// ---------------------------------------------------------------------------
__global__ void __launch_bounds__(256) k_adjsweep(
    const float* __restrict__ x, float* __restrict__ out,
    float* __restrict__ gss, float4* __restrict__ gbox,
    const u64* __restrict__ skeys, const int* __restrict__ counter,
    u64* __restrict__ adjT, u32* __restrict__ flags, int ws_ok)
{
    __shared__ __align__(16) union ShU {
        struct { float4 lb[FAST_CAP]; float la[FAST_CAP]; } p;   // producers
        struct { u64 buf[2][16][34]; u64 keepw[NCH]; } c;        // consumer
    } sh;

    const int tid = threadIdx.x, lane = tid & 63, wv = tid >> 6;
    const int b = blockIdx.x;

    int M = counter[0]; if (M > NB) M = NB;
    const bool fast = (M <= FAST_CAP) && ws_ok;
    const int W = (M + 63) >> 6;

    if (b != 0) {
        // ===================== producer =====================
        const int g = b - 1;                   // row group: rows 16g..16g+15
        if (!fast) return;
        if ((g << 4) >= M) {
            if (tid == 0)
                __hip_atomic_store(&flags[g], 1u, __ATOMIC_RELEASE, __HIP_MEMORY_SCOPE_AGENT);
            return;
        }
        for (int f = tid; f < M; f += 256) {
            float4 bb = gbox[f];
            sh.p.lb[f] = bb;
            sh.p.la[f] = __fmul_rn(__fsub_rn(bb.z, bb.x), __fsub_rn(bb.w, bb.y));
        }
        __syncthreads();
        #pragma unroll
        for (int r = 0; r < 4; ++r) {
            int i = (g << 4) + (r << 2) + wv;
            if (i >= M) break;
            float4 bi = sh.p.lb[i];
            float iar = sh.p.la[i];
            for (int kk = 0; kk < W; ++kk) {
                int j = (kk << 6) + lane;
                float4 bj = sh.p.lb[j & (FAST_CAP - 1)];
                float jar = sh.p.la[j & (FAST_CAP - 1)];
                int hit = (j < M) && iou_hit_nodiv(bi.x, bi.y, bi.z, bi.w, iar,
                                                   bj.x, bj.y, bj.z, bj.w, jar);
                u64 mm = __ballot(hit);
                if (lane == 0) adjT[((size_t)kk << 10) + i] = mm;
            }
        }
        __syncthreads();                       // drains all waves' adjT stores
        if (tid == 0) {
            __threadfence();                   // agent-scope visibility
            __hip_atomic_store(&flags[g], 1u, __ATOMIC_RELEASE, __HIP_MEMORY_SCOPE_AGENT);
        }
        return;
    }

    // ===================== consumer (block 0) =====================
    if (fast) {
        const int nrb = (M + 31) >> 5;
        const int ngroups = (M + 15) >> 4;     // <= 64
        const int wl = (lane < W) ? lane : 0;
        const ulonglong2* gp2 = (const ulonglong2*)adjT;

        u32 supl = 0u, suph = 0u, dl = 0u, dh = 0u;
        u64 mykw = 0ull;

        if (nrb > 0) {
            {   // prologue: stage row-block 0 into buf[0], one pair/thread
                int w = tid >> 4, tt = tid & 15;
                int g = tt >> 3;
                if (g < ngroups) {
                    while (__hip_atomic_load(&flags[g], __ATOMIC_ACQUIRE,
                                             __HIP_MEMORY_SCOPE_AGENT) == 0u)
                        __builtin_amdgcn_s_sleep(2);
                }
                ulonglong2 v = gp2[(w << 9) | tt];
                *(ulonglong2*)&sh.c.buf[0][w][2 * tt] = v;
            }
            __syncthreads();

            for (int rb = 0; rb < nrb; ++rb) {
                const int pbi = rb & 1;
                const int rbn = rb + 1;
                if (tid >= 64) {
                    // waves 1-3: JIT stage row-block rb+1 into buf[pbi^1]
                    if (rbn < nrb) {
                        const int p2a = tid - 64;            // 0..191
                        const int wA = p2a >> 4, ttA = p2a & 15;
                        const int gA = (rbn << 1) + (ttA >> 3);
                        if (gA < ngroups) {
                            while (__hip_atomic_load(&flags[gA], __ATOMIC_ACQUIRE,
                                                     __HIP_MEMORY_SCOPE_AGENT) == 0u)
                                __builtin_amdgcn_s_sleep(2);
                        }
                        ulonglong2 va = gp2[(wA << 9) | ((rbn << 4) + ttA)];
                        const int p2b = p2a + 192;
                        const bool hasB = (p2b < 256);
                        int wB = 0, ttB = 0;
                        ulonglong2 vb = make_ulonglong2(0ull, 0ull);
                        if (hasB) {
                            wB = p2b >> 4; ttB = p2b & 15;
                            const int gB = (rbn << 1) + (ttB >> 3);
                            if (gB < ngroups) {
                                while (__hip_atomic_load(&flags[gB], __ATOMIC_ACQUIRE,
                                                         __HIP_MEMORY_SCOPE_AGENT) == 0u)
                                    __builtin_amdgcn_s_sleep(2);
                            }
                            vb = gp2[(wB << 9) | ((rbn << 4) + ttB)];
                        }
                        *(ulonglong2*)&sh.c.buf[pbi ^ 1][wA][2 * ttA] = va;
                        if (hasB) *(ulonglong2*)&sh.c.buf[pbi ^ 1][wB][2 * ttB] = vb;
                    }
                } else {
                    // wave 0: validated decision/OR chain on buf[pbi]
                    const int c = rb >> 1;
                    const ulonglong2* crow = (const ulonglong2*)&sh.c.buf[pbi][c][0];
                    const ulonglong2* rrow = (const ulonglong2*)&sh.c.buf[pbi][wl][0];
                    u64 colb[32], rowb[32];
                    #pragma unroll
                    for (int q = 0; q < 16; ++q) {
                        ulonglong2 t2 = crow[q];
                        colb[2 * q] = t2.x; colb[2 * q + 1] = t2.y;
                    }
                    #pragma unroll
                    for (int q = 0; q < 16; ++q) {
                        ulonglong2 t2 = rrow[q];
                        rowb[2 * q] = t2.x; rowb[2 * q + 1] = t2.y;
                    }
                    if (!(rb & 1)) {
                        if (rb == 0) { dl = 0u; dh = 0u; }
                        else { dl = (u32)__shfl((int)supl, c); dh = (u32)__shfl((int)suph, c); }
                        int rem = M - (c << 6);           // tail: rows >= M suppressed
                        if (rem < 64) {
                            if (rem >= 32) dh |= 0xFFFFFFFFu << (rem - 32);
                            else { dh = 0xFFFFFFFFu; dl |= 0xFFFFFFFFu << rem; }
                        }
                    }
                    u32 kw = 0u;
                    if (!(rb & 1)) {
                        #pragma unroll
                        for (int t = 0; t < 32; ++t) {
                            u32 bbit = (dl >> t) & 1u;
                            u32 m = bbit - 1u;            // ~0 kept, 0 suppressed
                            dl |= (u32)colb[t] & m;
                            dh |= (u32)(colb[t] >> 32) & m;
                            kw |= m & (1u << t);
                        }
                    } else {
                        #pragma unroll
                        for (int t = 0; t < 32; ++t) {
                            u32 bbit = (dh >> t) & 1u;
                            u32 m = bbit - 1u;
                            dl |= (u32)colb[t] & m;
                            dh |= (u32)(colb[t] >> 32) & m;
                            kw |= m & (1u << t);
                        }
                    }
                    #pragma unroll
                    for (int t = 0; t < 32; ++t) {
                        u32 m = 0u - ((kw >> t) & 1u);    // ~0 if kept
                        supl |= (u32)rowb[t] & m;
                        suph |= (u32)(rowb[t] >> 32) & m;
                    }
                    mykw |= (lane == c) ? ((u64)kw << ((rb & 1) << 5)) : 0ull;
                }
                __syncthreads();
            }
        }
        if (tid < 64) sh.c.keepw[lane] = mykw;
    } else {
        // slow path (M > 1024): counting rank + decode + single-wave sweep.
        for (int t = tid; t < M; t += 256) {
            u64 key = skeys[t];
            int r = 0;
            for (int q = 0; q < M; ++q) r += (skeys[q] > key) ? 1 : 0;
            int n = NB - 1 - (int)(key & 0xFFFFFFFFull);
            float X1, Y1, X2, Y2;
            decode_box(x, n, X1, Y1, X2, Y2);
            gbox[r] = make_float4(X1, Y1, X2, Y2);
            gss[r] = __uint_as_float((u32)(key >> 32));
        }
        __threadfence();
        __syncthreads();
        if (tid < 64) {
            u64 kbs[3] = {0ull, 0ull, 0ull};
            for (int i = 0; i < M; ++i) {
                float4 bi = gbox[i];
                float iar = __fmul_rn(__fsub_rn(bi.z, bi.x), __fsub_rn(bi.w, bi.y));
                int hit = 0;
                int nk = (i > lane) ? ((i - lane + 63) >> 6) : 0;
                for (int w = 0; w < 3 && !hit; ++w) {
                    int klim = nk - (w << 6);
                    if (klim <= 0) break;
                    u64 bits = kbs[w];
                    if (klim < 64) bits &= ((1ull << klim) - 1ull);
                    while (bits) {
                        int kk2 = __builtin_ctzll(bits);
                        bits &= bits - 1ull;
                        int jj = lane + (((w << 6) + kk2) << 6);
                        float4 bj = gbox[jj];
                        float jar = __fmul_rn(__fsub_rn(bj.z, bj.x), __fsub_rn(bj.w, bj.y));
                        if (iou_hit_div(bi.x, bi.y, bi.z, bi.w, iar,
                                        bj.x, bj.y, bj.z, bj.w, jar)) { hit = 1; break; }
                    }
                }
                int suppressed = __any(hit);
                if (!suppressed && lane == (i & 63)) kbs[(i >> 6) >> 6] |= 1ull << ((i >> 6) & 63);
            }
            int NWrd = (M + 63) >> 6;
            for (int wd = 0; wd < NWrd; ++wd) {
                u64 bit = (kbs[wd >> 6] >> (wd & 63)) & 1ull;
                u64 word = __ballot(bit != 0);
                if (lane == 0 && wd < NCH) sh.c.keepw[wd] = word;
            }
        }
    }
    __syncthreads();

    // emit kept rows only (rest zeroed in dispatch 1)
    for (int i = tid; i < M; i += 256) {
        if ((sh.c.keepw[i >> 6] >> (i & 63)) & 1ull) {
            float4 bb = gbox[i];
            out[i * 5 + 0] = gss[i];
            out[i * 5 + 1] = bb.x;
            out[i * 5 + 2] = bb.y;
            out[i * 5 + 3] = __fsub_rn(bb.z, bb.x);
            out[i * 5 + 4] = __fsub_rn(bb.w, bb.y);
            out[5 * NB + i] = 1.0f;
        }
    }
}

extern "C" void kernel_launch(void* const* d_in, const int* in_sizes, int n_in,
                              void* d_out, int out_size, void* d_ws, size_t ws_size,
                              hipStream_t stream) {
    const float* x = (const float*)d_in[0];
    float* out = (float*)d_out;

    char* ws = (char*)d_ws;
    int* counter = (int*)ws;
    float*  gss  = (float*)(ws + 16);
    float4* gbox = (float4*)(ws + 16 + (size_t)4 * NB);
    u64*    adjT = (u64*)(ws + 16 + (size_t)4 * NB + (size_t)16 * NB);
    u64*    skeys = (u64*)((char*)adjT + (size_t)16384 * 8);
    u32*    flags = (u32*)((char*)skeys + (size_t)8 * NB);
    const size_t NEEDED = 16 + (size_t)4 * NB + (size_t)16 * NB
                        + (size_t)16384 * 8 + (size_t)8 * NB + 256;   // 389,392
    int ws_ok = (ws_size >= NEEDED) ? 1 : 0;

    k_sort<<<16, 256, 0, stream>>>(x, out, gss, gbox, skeys, counter, flags, ws_ok);
    k_adjsweep<<<65, 256, 0, stream>>>(x, out, gss, gbox, skeys, counter, adjT, flags, ws_ok);
}

// Round 5
// 104.678 us; speedup vs baseline: 1.3253x; 1.0826x over previous
//
#include <hip/hip_runtime.h>

#define PP 96
#define NB (PP*PP)            // 9216
#define NCH (NB/64)           // 144 64-chunks
#define PROB_THR 0.9f
#define FAST_CAP 1024         // fast path: M <= 1024, W <= 16
#define LSTRIDE 1034          // padded LDS row stride (u64): even (16B), 2-way max aliasing

typedef unsigned long long u64;
typedef unsigned int u32;

// Bit-identical decode core (no FMA contraction; rintf == round-half-even).
__device__ __forceinline__ void decode_core(int n, float xv, float yv, float wv, float hv,
                                            float& X1, float& Y1, float& X2, float& Y2)
{
    int i = n / PP;
    int j = n - i * PP;
    float bx = __fadd_rn(__fmul_rn(xv, 16.0f), (float)i * 16.0f);
    float by = __fadd_rn(__fmul_rn(yv, 16.0f), (float)j * 16.0f);
    float bw = __fmul_rn(wv, 1536.0f);
    float bh = __fmul_rn(hv, 1536.0f);
    X1 = rintf(bx);
    Y1 = rintf(by);
    X2 = rintf(__fadd_rn(bw, bx));
    Y2 = rintf(__fadd_rn(bh, by));
}

__device__ __forceinline__ void decode_box(const float* __restrict__ x, int n,
                                           float& X1, float& Y1, float& X2, float& Y2)
{
    decode_core(n, x[NB + n], x[2 * NB + n], x[3 * NB + n], x[4 * NB + n], X1, Y1, X2, Y2);
}

// Exact-equivalent IoU>0.5 without division (validated on HW).
__device__ __forceinline__ int iou_hit_nodiv(float ix1, float iy1, float ix2, float iy2, float iar,
                                             float jx1, float jy1, float jx2, float jy2, float jar)
{
    float xx1 = fmaxf(ix1, jx1), yy1 = fmaxf(iy1, jy1);
    float xx2 = fminf(ix2, jx2), yy2 = fminf(iy2, jy2);
    float iw = fmaxf(__fsub_rn(xx2, xx1), 0.0f);
    float ih = fmaxf(__fsub_rn(yy2, yy1), 0.0f);
    float inter = __fmul_rn(iw, ih);
    float uni = __fsub_rn(__fadd_rn(iar, jar), inter);
    return (uni > 0.0f && __fadd_rn(inter, inter) > uni) ? 1 : 0;
}

__device__ __forceinline__ int iou_hit_div(float ix1, float iy1, float ix2, float iy2, float iar,
                                           float jx1, float jy1, float jx2, float jy2, float jar)
{
    float xx1 = fmaxf(ix1, jx1), yy1 = fmaxf(iy1, jy1);
    float xx2 = fminf(ix2, jx2), yy2 = fminf(iy2, jy2);
    float iw = fmaxf(__fsub_rn(xx2, xx1), 0.0f);
    float ih = fmaxf(__fsub_rn(yy2, yy1), 0.0f);
    float inter = __fmul_rn(iw, ih);
    float uni = __fsub_rn(__fadd_rn(iar, jar), inter);
    return (uni > 0.0f && __fdiv_rn(inter, uni) > 0.5f) ? 1 : 0;
}

// ---------------------------------------------------------------------------
// Dispatch 1: k_sort, 16 blocks x 256 — EXACT R0 structure (rank-own-64,
// ~5us), plus fire-and-forget out-zeroing and done-counter zeroing (ordered
// before dispatch 2 by the dispatch boundary).
// ---------------------------------------------------------------------------
__global__ void __launch_bounds__(256) k_sort(
    const float* __restrict__ x, float* __restrict__ out,
    float* __restrict__ gss, float4* __restrict__ gbox,
    u64* __restrict__ skeys, int* __restrict__ counter,
    int* __restrict__ done, int ws_ok)
{
    __shared__ u64 lmask[NCH];
    __shared__ int pc[NCH], loff[NCH];
    __shared__ int sM;
    __shared__ u64 kdb[FAST_CAP];
    __shared__ int prank[256];

    const int tid = threadIdx.x;
    const int lane = tid & 63;
    const int wv = tid >> 6;                  // 4 waves; 36 chunks each
    const int b = blockIdx.x;

    // fire-and-forget: zero out (6*NB floats = 13824 float4 over 16 blocks)
    {
        float4 z4 = make_float4(0.f, 0.f, 0.f, 0.f);
        for (int q = tid; q < 864; q += 256)
            ((float4*)out)[b * 864 + q] = z4;
        if (b == 0 && tid == 0) done[0] = 0;
    }

    #pragma unroll
    for (int g = 0; g < 36; g += 6) {
        float sv[6];
        #pragma unroll
        for (int u = 0; u < 6; ++u)
            sv[u] = x[((wv * 36 + g + u) << 6) + lane];
        #pragma unroll
        for (int u = 0; u < 6; ++u) {
            u64 m = __ballot(sv[u] > PROB_THR);
            if (lane == 0) lmask[wv * 36 + g + u] = m;
        }
    }
    __syncthreads();
    if (tid < NCH) pc[tid] = __popcll(lmask[tid]);
    __syncthreads();
    if (tid < 64) {                           // wave-parallel prefix (validated)
        int acc = 0;
        for (int seg = 0; seg < 3; ++seg) {
            int c = (seg << 6) + lane;
            int pv = (c < NCH) ? pc[c] : 0;
            int v = pv;
            #pragma unroll
            for (int off = 1; off < 64; off <<= 1) {
                int u = __shfl_up(v, off);
                if (lane >= off) v += u;
            }
            if (c < NCH) loff[c] = acc + v - pv;
            acc += __shfl(v, 63);
        }
        if (lane == 0) sM = acc;
    }
    __syncthreads();
    const int M = sM;
    const bool fast = (M <= FAST_CAP) && ws_ok;
    if (b == 0 && tid == 0) counter[0] = M;

    if (!fast) {
        if (b == 0) {
            for (int c = wv; c < NCH; c += 4) {
                float s = x[(c << 6) + lane];
                u64 m = lmask[c];
                if ((m >> lane) & 1ull) {
                    int pos = loff[c] + __popcll(m & ((1ull << lane) - 1ull));
                    int n = (c << 6) + lane;
                    skeys[pos] = ((u64)__float_as_uint(s) << 32) | (u64)(NB - 1 - n);
                }
            }
        }
        return;
    }

    for (int c = wv; c < NCH; c += 4) {
        float s = x[(c << 6) + lane];          // L1-warm
        u64 m = lmask[c];
        if ((m >> lane) & 1ull) {
            int pos = loff[c] + __popcll(m & ((1ull << lane) - 1ull));
            int n = (c << 6) + lane;
            kdb[pos] = ((u64)__float_as_uint(s) << 32) | (u64)(NB - 1 - n);
        }
    }
    for (int q = M + tid; q < FAST_CAP; q += 256) kdb[q] = 0ull;  // pad
    __syncthreads();

    const int cand = (b << 6) + lane;          // < 1024 always
    const u64 k0 = kdb[cand];
    const int n0 = NB - 1 - (int)(k0 & 0xFFFFFFFFull);
    float xv0 = x[NB + n0], yv0 = x[2 * NB + n0];
    float wv0 = x[3 * NB + n0], hv0 = x[4 * NB + n0];
    int r = 0;
    const int nck = (M + 63) >> 6;
    for (int ch = wv; ch < nck; ch += 4) {     // wave-uniform chunk slice
        u64 kq = kdb[(ch << 6) + lane];
        u32 qlo = (u32)kq, qhi = (u32)(kq >> 32);
        #pragma unroll
        for (int i = 0; i < 64; ++i) {
            u32 blo = (u32)__builtin_amdgcn_readlane((int)qlo, i);
            u32 bhi = (u32)__builtin_amdgcn_readlane((int)qhi, i);
            u64 kb = ((u64)bhi << 32) | (u64)blo;
            r += (kb > k0) ? 1 : 0;
        }
    }
    prank[tid] = r;
    __syncthreads();
    if (tid < 64 && cand < M) {
        int rk = prank[tid] + prank[64 + tid] + prank[128 + tid] + prank[192 + tid];
        float X1, Y1, X2, Y2;
        decode_core(n0, xv0, yv0, wv0, hv0, X1, Y1, X2, Y2);
        gbox[rk] = make_float4(X1, Y1, X2, Y2);
        gss[rk] = __uint_as_float((u32)(k0 >> 32));
    }
}

// ---------------------------------------------------------------------------
// Dispatch 2: k_adjsweep, 65 blocks x 256 — single-handshake fusion.
// Blocks 1..64: EXACT R0 k_adj body for 16 rows each, then ONE release
//   fetch_add on done (after a block-wide store drain).
// Block 0: thread 0 spins (acquire) until done==64 — ONE coherence event,
//   not per-iteration (R4's 384 acquire-invalidates/iter were the 60us) —
//   then runs the byte-identical R0 k_sweep (staged LDS + decision chain).
// Deadlock-free: producers never wait; 65 blocks all co-resident; even
//   without co-residency producers don't depend on the consumer.
// ---------------------------------------------------------------------------
__global__ void __launch_bounds__(256) k_adjsweep(
    const float* __restrict__ x, float* __restrict__ out,
    float* __restrict__ gss, float4* __restrict__ gbox,
    const u64* __restrict__ skeys, const int* __restrict__ counter,
    u64* __restrict__ adjT, int* __restrict__ done, int ws_ok)
{
    __shared__ __align__(16) union ShU {
        struct { float4 lb[FAST_CAP]; float la[FAST_CAP]; } p;     // producers
        struct { u64 Lds[16 * LSTRIDE]; u64 keepw[NCH]; } c;       // consumer
    } sh;

    const int tid = threadIdx.x, lane = tid & 63, wv = tid >> 6;
    const int b = blockIdx.x;

    int M = counter[0]; if (M > NB) M = NB;
    const bool fast = (M <= FAST_CAP) && ws_ok;
    const int W = (M + 63) >> 6;

    if (b != 0) {
        // ===================== producer (exact R0 k_adj body) ==============
        if (!fast) return;
        const int g = b - 1;                   // rows 16g..16g+15
        if ((g << 4) >= M) {
            if (tid == 0)
                __hip_atomic_fetch_add(done, 1, __ATOMIC_RELEASE, __HIP_MEMORY_SCOPE_AGENT);
            return;
        }
        for (int f = tid; f < M; f += 256) {
            float4 bb = gbox[f];
            sh.p.lb[f] = bb;
            sh.p.la[f] = __fmul_rn(__fsub_rn(bb.z, bb.x), __fsub_rn(bb.w, bb.y));
        }
        __syncthreads();
        #pragma unroll
        for (int r = 0; r < 4; ++r) {
            int i = (g << 4) + (r << 2) + wv;
            if (i >= M) break;
            float4 bi = sh.p.lb[i];
            float iar = sh.p.la[i];
            for (int kk = 0; kk < W; ++kk) {
                int j = (kk << 6) + lane;
                float4 bj = sh.p.lb[j & (FAST_CAP - 1)];
                float jar = sh.p.la[j & (FAST_CAP - 1)];
                int hit = (j < M) && iou_hit_nodiv(bi.x, bi.y, bi.z, bi.w, iar,
                                                   bj.x, bj.y, bj.z, bj.w, jar);
                u64 mm = __ballot(hit);
                if (lane == 0) adjT[((size_t)kk << 10) + i] = mm;
            }
        }
        __syncthreads();                       // all waves' adjT stores issued
        if (tid == 0)
            __hip_atomic_fetch_add(done, 1, __ATOMIC_RELEASE, __HIP_MEMORY_SCOPE_AGENT);
        return;
    }

    // ===================== consumer (block 0) ==============================
    if (fast) {
        // ---- single handshake: thread 0 waits for all 64 producers ----
        if (tid == 0) {
            while (__hip_atomic_load(done, __ATOMIC_ACQUIRE,
                                     __HIP_MEMORY_SCOPE_AGENT) < 64)
                __builtin_amdgcn_s_sleep(2);
        }
        __syncthreads();

        // ---- stage adjT -> LDS: 4 rounds x 8-deep batched 16B (validated) ----
        const int npair = W << 9;                     // <= 8192 ulonglong2
        const ulonglong2* gp = (const ulonglong2*)adjT;
        for (int r = 0; r < 4; ++r) {
            int fb = (r << 11) + tid;
            ulonglong2 v[8];
            #pragma unroll
            for (int u = 0; u < 8; ++u) {
                int f = fb + (u << 8);
                v[u] = (f < npair) ? gp[f] : make_ulonglong2(0ull, 0ull);
            }
            #pragma unroll
            for (int u = 0; u < 8; ++u) {
                int f = fb + (u << 8);
                if (f < npair) {
                    int w = f >> 9, r2 = f & 511;
                    ((ulonglong2*)sh.c.Lds)[w * (LSTRIDE >> 1) + r2] = v[u];
                }
            }
        }
        __syncthreads();

        if (tid < 64) {
            const int wl = (lane < W) ? lane : 0;
            u32 supl = 0u, suph = 0u, dl = 0u, dh = 0u;
            u64 mykw = 0ull;
            const int nrb = (M + 31) >> 5;
            for (int rb = 0; rb < nrb; ++rb) {
                const int c = rb >> 1;
                const int base = rb << 5;
                const ulonglong2* crow = (const ulonglong2*)(sh.c.Lds + (size_t)c * LSTRIDE + base);
                const ulonglong2* rrow = (const ulonglong2*)(sh.c.Lds + (size_t)wl * LSTRIDE + base);
                // batch-issue BOTH columns as 32 independent b128 reads -> regs
                u64 colb[32], rowb[32];
                #pragma unroll
                for (int q = 0; q < 16; ++q) {
                    ulonglong2 t2 = crow[q];
                    colb[2 * q] = t2.x; colb[2 * q + 1] = t2.y;
                }
                #pragma unroll
                for (int q = 0; q < 16; ++q) {
                    ulonglong2 t2 = rrow[q];
                    rowb[2 * q] = t2.x; rowb[2 * q + 1] = t2.y;
                }
                if (!(rb & 1)) {
                    if (rb == 0) { dl = 0u; dh = 0u; }
                    else { dl = (u32)__shfl((int)supl, c); dh = (u32)__shfl((int)suph, c); }
                    int rem = M - (c << 6);           // tail: rows >= M suppressed
                    if (rem < 64) {
                        if (rem >= 32) dh |= 0xFFFFFFFFu << (rem - 32);
                        else { dh = 0xFFFFFFFFu; dl |= 0xFFFFFFFFu << rem; }
                    }
                }
                u32 kw = 0u;
                if (!(rb & 1)) {
                    #pragma unroll
                    for (int t = 0; t < 32; ++t) {
                        u32 bbit = (dl >> t) & 1u;
                        u32 m = bbit - 1u;            // ~0 kept, 0 suppressed
                        dl |= (u32)colb[t] & m;
                        dh |= (u32)(colb[t] >> 32) & m;
                        kw |= m & (1u << t);
                    }
                } else {
                    #pragma unroll
                    for (int t = 0; t < 32; ++t) {
                        u32 bbit = (dh >> t) & 1u;
                        u32 m = bbit - 1u;
                        dl |= (u32)colb[t] & m;
                        dh |= (u32)(colb[t] >> 32) & m;
                        kw |= m & (1u << t);
                    }
                }
                // constant-trip masked suppression-OR (values already in regs)
                #pragma unroll
                for (int t = 0; t < 32; ++t) {
                    u32 m = 0u - ((kw >> t) & 1u);    // ~0 if kept
                    supl |= (u32)rowb[t] & m;
                    suph |= (u32)(rowb[t] >> 32) & m;
                }
                mykw |= (lane == c) ? ((u64)kw << ((rb & 1) << 5)) : 0ull;
            }
            sh.c.keepw[lane] = mykw;
        }
    } else {
        // slow path (M > 1024): counting rank + decode + single-wave sweep.
        for (int t = tid; t < M; t += 256) {
            u64 key = skeys[t];
            int r = 0;
            for (int q = 0; q < M; ++q) r += (skeys[q] > key) ? 1 : 0;
            int n = NB - 1 - (int)(key & 0xFFFFFFFFull);
            float X1, Y1, X2, Y2;
            decode_box(x, n, X1, Y1, X2, Y2);
            gbox[r] = make_float4(X1, Y1, X2, Y2);
            gss[r] = __uint_as_float((u32)(key >> 32));
        }
        __threadfence();
        __syncthreads();
        if (tid < 64) {
            u64 kbs[3] = {0ull, 0ull, 0ull};
            for (int i = 0; i < M; ++i) {
                float4 bi = gbox[i];
                float iar = __fmul_rn(__fsub_rn(bi.z, bi.x), __fsub_rn(bi.w, bi.y));
                int hit = 0;
                int nk = (i > lane) ? ((i - lane + 63) >> 6) : 0;
                for (int w = 0; w < 3 && !hit; ++w) {
                    int klim = nk - (w << 6);
                    if (klim <= 0) break;
                    u64 bits = kbs[w];
                    if (klim < 64) bits &= ((1ull << klim) - 1ull);
                    while (bits) {
                        int kk2 = __builtin_ctzll(bits);
                        bits &= bits - 1ull;
                        int jj = lane + (((w << 6) + kk2) << 6);
                        float4 bj = gbox[jj];
                        float jar = __fmul_rn(__fsub_rn(bj.z, bj.x), __fsub_rn(bj.w, bj.y));
                        if (iou_hit_div(bi.x, bi.y, bi.z, bi.w, iar,
                                        bj.x, bj.y, bj.z, bj.w, jar)) { hit = 1; break; }
                    }
                }
                int suppressed = __any(hit);
                if (!suppressed && lane == (i & 63)) kbs[(i >> 6) >> 6] |= 1ull << ((i >> 6) & 63);
            }
            int NWrd = (M + 63) >> 6;
            for (int wd = 0; wd < NWrd; ++wd) {
                u64 bit = (kbs[wd >> 6] >> (wd & 63)) & 1ull;
                u64 word = __ballot(bit != 0);
                if (lane == 0 && wd < NCH) sh.c.keepw[wd] = word;
            }
        }
    }
    __syncthreads();

    // emit kept rows only (rest zeroed in dispatch 1)
    for (int i = tid; i < M; i += 256) {
        if ((sh.c.keepw[i >> 6] >> (i & 63)) & 1ull) {
            float4 bb = gbox[i];
            out[i * 5 + 0] = gss[i];
            out[i * 5 + 1] = bb.x;
            out[i * 5 + 2] = bb.y;
            out[i * 5 + 3] = __fsub_rn(bb.z, bb.x);
            out[i * 5 + 4] = __fsub_rn(bb.w, bb.y);
            out[5 * NB + i] = 1.0f;
        }
    }
}

extern "C" void kernel_launch(void* const* d_in, const int* in_sizes, int n_in,
                              void* d_out, int out_size, void* d_ws, size_t ws_size,
                              hipStream_t stream) {
    const float* x = (const float*)d_in[0];
    float* out = (float*)d_out;

    char* ws = (char*)d_ws;
    int* counter = (int*)ws;
    int* done    = (int*)(ws + 8);
    float*  gss  = (float*)(ws + 16);
    float4* gbox = (float4*)(ws + 16 + (size_t)4 * NB);
    u64*    adjT = (u64*)(ws + 16 + (size_t)4 * NB + (size_t)16 * NB);
    u64*    skeys = (u64*)((char*)adjT + (size_t)16384 * 8);
    const size_t NEEDED = 16 + (size_t)4 * NB + (size_t)16 * NB
                        + (size_t)16384 * 8 + (size_t)8 * NB;      // 389,136
    int ws_ok = (ws_size >= NEEDED) ? 1 : 0;

    k_sort<<<16, 256, 0, stream>>>(x, out, gss, gbox, skeys, counter, done, ws_ok);
    k_adjsweep<<<65, 256, 0, stream>>>(x, out, gss, gbox, skeys, counter, adjT, done, ws_ok);
}